// Round 21
// baseline (161.837 us; speedup 1.0000x reference)
//
#include <hip/hip_runtime.h>

#define T_DIM 512
#define I_DIM 16
#define B_DIM 4096
#define K_CH 16            // steps per chunk; ring = 2 chains x 2 bufs x 16 steps = 64 KB
#define NCH  (T_DIM / K_CH)
#define PF   4             // x-prefetch depth per chain
#define SCL 2.885390081777927f   // 2*log2(e), folded into weights/biases

typedef _Float16 f16x8 __attribute__((ext_vector_type(8)));
typedef float f32x4 __attribute__((ext_vector_type(4)));
typedef __fp16 hf2v __attribute__((ext_vector_type(2)));

union Frag { f16x8 v; __fp16 e[8]; uint4 u; };

__device__ __forceinline__ float tanh_s(float u) {
    float e = __builtin_amdgcn_exp2f(u);
    return fmaf(-2.f, __builtin_amdgcn_rcpf(e + 1.f), 1.f);
}
__device__ __forceinline__ f16x8 pack8(float a0, float a1, float a2, float a3,
                                       float b0, float b1, float b2, float b3) {
    Frag f;
    hf2v p0 = __builtin_amdgcn_cvt_pkrtz(a0, a1);
    hf2v p1 = __builtin_amdgcn_cvt_pkrtz(a2, a3);
    hf2v p2 = __builtin_amdgcn_cvt_pkrtz(b0, b1);
    hf2v p3 = __builtin_amdgcn_cvt_pkrtz(b2, b3);
    f.e[0] = p0[0]; f.e[1] = p0[1]; f.e[2] = p1[0]; f.e[3] = p1[1];
    f.e[4] = p2[0]; f.e[5] = p2[1]; f.e[6] = p3[0]; f.e[7] = p3[1];
    return f.v;
}
__device__ __forceinline__ f16x8 tanhpack_s(f32x4 a, f32x4 b) {
    return pack8(tanh_s(a[0]), tanh_s(a[1]), tanh_s(a[2]), tanh_s(a[3]),
                 tanh_s(b[0]), tanh_s(b[1]), tanh_s(b[2]), tanh_s(b[3]));
}
// q-permuted A-frag loads (q(8g+j) = 4g+j | 16+4g+j-4), verified r15-r20
__device__ __forceinline__ f16x8 loadWq32s(const float* W, int row, int g) {
    float4 a = *reinterpret_cast<const float4*>(W + row * 32 + 4 * g);
    float4 b = *reinterpret_cast<const float4*>(W + row * 32 + 16 + 4 * g);
    return pack8(a.x*SCL, a.y*SCL, a.z*SCL, a.w*SCL, b.x*SCL, b.y*SCL, b.z*SCL, b.w*SCL);
}
__device__ __forceinline__ f16x8 loadWq16s(const float* W, int row, int g) {
    float4 a = *reinterpret_cast<const float4*>(W + row * 16 + 4 * g);
    return pack8(a.x*SCL, a.y*SCL, a.z*SCL, a.w*SCL, 0.f, 0.f, 0.f, 0.f);
}

// r19 producer-consumer structure with TWO independent batch chains per wave:
// chain B's instruction stream fills chain A's MFMA+tanh latency stall.
// 256 blocks x 2 waves; weights shared between chains.
__global__ void __launch_bounds__(128)
rnn2_dual_pc_kernel(const float* __restrict__ x,
                    const float* __restrict__ Wih0, const float* __restrict__ Whh0,
                    const float* __restrict__ bih0, const float* __restrict__ bhh0,
                    const float* __restrict__ Wih1, const float* __restrict__ Whh1,
                    const float* __restrict__ bih1, const float* __restrict__ bhh1,
                    const float* __restrict__ fcw, const float* __restrict__ fcb,
                    float* __restrict__ out)
{
    const int tid = threadIdx.x;
    const int l   = tid & 63;
    const int wid = tid >> 6;
    const int c   = l & 15;
    const int g   = l >> 4;
    const int rowA = blockIdx.x * 16;          // chain A: rows rowA..rowA+7
                                               // chain B: rows rowA+8..rowA+15
    __shared__ __fp16 ring[2][2][K_CH][64][8]; // [chain][buf][step][lane][8] = 64 KB

    f16x8 wT0[2], wT1[2];
    f32x4 bC[2];
    Frag h1A, h1B;
    f32x4 XaccA[2], XaccB[2];
    float4 xa0, xa1, xa2, xa3, xb0, xb1, xb2, xb3;
    const float *xlA = nullptr, *xlB = nullptr;
    float hA0=0.f,hA1=0.f,hA2=0.f,hA3=0.f,hA4=0.f,hA5=0.f,hA6=0.f,hA7=0.f;
    float hB0=0.f,hB1=0.f,hB2=0.f,hB3=0.f,hB4=0.f,hB5=0.f,hB6=0.f,hB7=0.f;
    Frag h2A, h2B;
    h2A.u = make_uint4(0u,0u,0u,0u);
    h2B.u = make_uint4(0u,0u,0u,0u);

    if (wid == 0) {   // producer: layer 1
#pragma unroll
        for (int tt = 0; tt < 2; ++tt) {
            const int row = c + 16 * tt;
            wT0[tt] = loadWq32s(Whh0, row, g);
            wT1[tt] = loadWq16s(Wih0, row, g);
            const int r0 = 4 * g + 16 * tt;
            float4 bi = *reinterpret_cast<const float4*>(bih0 + r0);
            float4 bh = *reinterpret_cast<const float4*>(bhh0 + r0);
            bC[tt][0] = (bi.x + bh.x) * SCL; bC[tt][1] = (bi.y + bh.y) * SCL;
            bC[tt][2] = (bi.z + bh.z) * SCL; bC[tt][3] = (bi.w + bh.w) * SCL;
        }
        xlA = x + (size_t)(rowA + (c & 7)) * (T_DIM * I_DIM) + 4 * g;
        xlB = xlA + (size_t)8 * (T_DIM * I_DIM);
    } else {          // consumer: layer 2 (wT0 = Wih1 for pd1, wT1 = Whh1 chain)
#pragma unroll
        for (int tt = 0; tt < 2; ++tt) {
            const int row = c + 16 * tt;
            wT0[tt] = loadWq32s(Wih1, row, g);
            wT1[tt] = loadWq32s(Whh1, row, g);
            const int r0 = 4 * g + 16 * tt;
            float4 bi = *reinterpret_cast<const float4*>(bih1 + r0);
            float4 bh = *reinterpret_cast<const float4*>(bhh1 + r0);
            bC[tt][0] = (bi.x + bh.x) * SCL; bC[tt][1] = (bi.y + bh.y) * SCL;
            bC[tt][2] = (bi.z + bh.z) * SCL; bC[tt][3] = (bi.w + bh.w) * SCL;
        }
    }

// one producer step for one chain; P holds x(t+1), reload x(t+PF+1)
#define PSTEP(t, P, H1, XA, XL, CH)                                                          \
    {                                                                                        \
        f32x4 D0a = __builtin_amdgcn_mfma_f32_16x16x32_f16(wT0[0], (H1).v, (XA)[0], 0,0,0);  \
        f32x4 D0b = __builtin_amdgcn_mfma_f32_16x16x32_f16(wT0[1], (H1).v, (XA)[1], 0,0,0);  \
        Frag xf; xf.v = pack8((P).x, (P).y, (P).z, (P).w, 0.f, 0.f, 0.f, 0.f);               \
        const int tn = ((t) + PF + 1 < T_DIM) ? (t) + PF + 1 : (T_DIM - 1);                  \
        (P) = *reinterpret_cast<const float4*>((XL) + (size_t)tn * I_DIM);                   \
        (H1).v = tanhpack_s(D0a, D0b);                                                       \
        *reinterpret_cast<uint4*>(&ring[CH][((t) / K_CH) & 1][(t) & (K_CH - 1)][l][0]) = (H1).u; \
        (XA)[0] = __builtin_amdgcn_mfma_f32_16x16x32_f16(wT1[0], xf.v, bC[0], 0,0,0);        \
        (XA)[1] = __builtin_amdgcn_mfma_f32_16x16x32_f16(wT1[1], xf.v, bC[1], 0,0,0);        \
    }

#pragma unroll 1
    for (int p = 0; p <= NCH; ++p) {
        if (wid == 0 && p < NCH) {
            if (p == 0) {
                // ---- serial prologue: steps 0..PF-1, both chains interleaved ----
#pragma unroll
                for (int t = 0; t < PF; ++t) {
                    float4 qa = *reinterpret_cast<const float4*>(xlA + (size_t)t * I_DIM);
                    float4 qb = *reinterpret_cast<const float4*>(xlB + (size_t)t * I_DIM);
                    Frag ga; ga.v = pack8(qa.x, qa.y, qa.z, qa.w, 0.f, 0.f, 0.f, 0.f);
                    Frag gb; gb.v = pack8(qb.x, qb.y, qb.z, qb.w, 0.f, 0.f, 0.f, 0.f);
                    f32x4 XA0 = __builtin_amdgcn_mfma_f32_16x16x32_f16(wT1[0], ga.v, bC[0], 0,0,0);
                    f32x4 XA1 = __builtin_amdgcn_mfma_f32_16x16x32_f16(wT1[1], ga.v, bC[1], 0,0,0);
                    f32x4 XB0 = __builtin_amdgcn_mfma_f32_16x16x32_f16(wT1[0], gb.v, bC[0], 0,0,0);
                    f32x4 XB1 = __builtin_amdgcn_mfma_f32_16x16x32_f16(wT1[1], gb.v, bC[1], 0,0,0);
                    f32x4 DA0, DA1, DB0, DB1;
                    if (t == 0) { DA0 = XA0; DA1 = XA1; DB0 = XB0; DB1 = XB1; }
                    else {
                        DA0 = __builtin_amdgcn_mfma_f32_16x16x32_f16(wT0[0], h1A.v, XA0, 0,0,0);
                        DA1 = __builtin_amdgcn_mfma_f32_16x16x32_f16(wT0[1], h1A.v, XA1, 0,0,0);
                        DB0 = __builtin_amdgcn_mfma_f32_16x16x32_f16(wT0[0], h1B.v, XB0, 0,0,0);
                        DB1 = __builtin_amdgcn_mfma_f32_16x16x32_f16(wT0[1], h1B.v, XB1, 0,0,0);
                    }
                    h1A.v = tanhpack_s(DA0, DA1);
                    h1B.v = tanhpack_s(DB0, DB1);
                    *reinterpret_cast<uint4*>(&ring[0][0][t][l][0]) = h1A.u;
                    *reinterpret_cast<uint4*>(&ring[1][0][t][l][0]) = h1B.u;
                }
                // Xacc = fold x(PF); fill prefetch rings with x(PF+1 .. PF+4)
                {
                    float4 qa = *reinterpret_cast<const float4*>(xlA + (size_t)PF * I_DIM);
                    float4 qb = *reinterpret_cast<const float4*>(xlB + (size_t)PF * I_DIM);
                    Frag ga; ga.v = pack8(qa.x, qa.y, qa.z, qa.w, 0.f, 0.f, 0.f, 0.f);
                    Frag gb; gb.v = pack8(qb.x, qb.y, qb.z, qb.w, 0.f, 0.f, 0.f, 0.f);
                    XaccA[0] = __builtin_amdgcn_mfma_f32_16x16x32_f16(wT1[0], ga.v, bC[0], 0,0,0);
                    XaccA[1] = __builtin_amdgcn_mfma_f32_16x16x32_f16(wT1[1], ga.v, bC[1], 0,0,0);
                    XaccB[0] = __builtin_amdgcn_mfma_f32_16x16x32_f16(wT1[0], gb.v, bC[0], 0,0,0);
                    XaccB[1] = __builtin_amdgcn_mfma_f32_16x16x32_f16(wT1[1], gb.v, bC[1], 0,0,0);
                }
                xa0 = *reinterpret_cast<const float4*>(xlA + (PF + 1) * I_DIM);
                xa1 = *reinterpret_cast<const float4*>(xlA + (PF + 2) * I_DIM);
                xa2 = *reinterpret_cast<const float4*>(xlA + (PF + 3) * I_DIM);
                xa3 = *reinterpret_cast<const float4*>(xlA + (PF + 4) * I_DIM);
                xb0 = *reinterpret_cast<const float4*>(xlB + (PF + 1) * I_DIM);
                xb1 = *reinterpret_cast<const float4*>(xlB + (PF + 2) * I_DIM);
                xb2 = *reinterpret_cast<const float4*>(xlB + (PF + 3) * I_DIM);
                xb3 = *reinterpret_cast<const float4*>(xlB + (PF + 4) * I_DIM);
                // steps PF..K_CH-1 (12 = 3 groups of 4), chains interleaved
#pragma unroll 1
                for (int sg = PF; sg < K_CH; sg += 4) {
                    PSTEP(sg + 0, xa0, h1A, XaccA, xlA, 0) PSTEP(sg + 0, xb0, h1B, XaccB, xlB, 1)
                    PSTEP(sg + 1, xa1, h1A, XaccA, xlA, 0) PSTEP(sg + 1, xb1, h1B, XaccB, xlB, 1)
                    PSTEP(sg + 2, xa2, h1A, XaccA, xlA, 0) PSTEP(sg + 2, xb2, h1B, XaccB, xlB, 1)
                    PSTEP(sg + 3, xa3, h1A, XaccA, xlA, 0) PSTEP(sg + 3, xb3, h1B, XaccB, xlB, 1)
                }
            } else {
                const int t0 = p * K_CH;
#pragma unroll 1
                for (int sg = 0; sg < K_CH; sg += 4) {
                    PSTEP(t0 + sg + 0, xa0, h1A, XaccA, xlA, 0) PSTEP(t0 + sg + 0, xb0, h1B, XaccB, xlB, 1)
                    PSTEP(t0 + sg + 1, xa1, h1A, XaccA, xlA, 0) PSTEP(t0 + sg + 1, xb1, h1B, XaccB, xlB, 1)
                    PSTEP(t0 + sg + 2, xa2, h1A, XaccA, xlA, 0) PSTEP(t0 + sg + 2, xb2, h1B, XaccB, xlB, 1)
                    PSTEP(t0 + sg + 3, xa3, h1A, XaccA, xlA, 0) PSTEP(t0 + sg + 3, xb3, h1B, XaccB, xlB, 1)
                }
            }
        }
        if (wid == 1 && p >= 1) {
            const int buf = (p - 1) & 1;
            Frag rA; rA.u = *reinterpret_cast<const uint4*>(&ring[0][buf][0][l][0]);
            f32x4 pdAa = __builtin_amdgcn_mfma_f32_16x16x32_f16(wT0[0], rA.v, bC[0], 0,0,0);
            f32x4 pdAb = __builtin_amdgcn_mfma_f32_16x16x32_f16(wT0[1], rA.v, bC[1], 0,0,0);
            Frag rB; rB.u = *reinterpret_cast<const uint4*>(&ring[1][buf][0][l][0]);
            f32x4 pdBa = __builtin_amdgcn_mfma_f32_16x16x32_f16(wT0[0], rB.v, bC[0], 0,0,0);
            f32x4 pdBb = __builtin_amdgcn_mfma_f32_16x16x32_f16(wT0[1], rB.v, bC[1], 0,0,0);
#pragma unroll 2
            for (int s = 0; s < K_CH; ++s) {
                f32x4 DAa = __builtin_amdgcn_mfma_f32_16x16x32_f16(wT1[0], h2A.v, pdAa, 0,0,0);
                f32x4 DAb = __builtin_amdgcn_mfma_f32_16x16x32_f16(wT1[1], h2A.v, pdAb, 0,0,0);
                f32x4 DBa = __builtin_amdgcn_mfma_f32_16x16x32_f16(wT1[0], h2B.v, pdBa, 0,0,0);
                f32x4 DBb = __builtin_amdgcn_mfma_f32_16x16x32_f16(wT1[1], h2B.v, pdBb, 0,0,0);
                const int sn = (s + 1 < K_CH) ? s + 1 : s;
                rA.u = *reinterpret_cast<const uint4*>(&ring[0][buf][sn][l][0]);
                pdAa = __builtin_amdgcn_mfma_f32_16x16x32_f16(wT0[0], rA.v, bC[0], 0,0,0);
                pdAb = __builtin_amdgcn_mfma_f32_16x16x32_f16(wT0[1], rA.v, bC[1], 0,0,0);
                rB.u = *reinterpret_cast<const uint4*>(&ring[1][buf][sn][l][0]);
                pdBa = __builtin_amdgcn_mfma_f32_16x16x32_f16(wT0[0], rB.v, bC[0], 0,0,0);
                pdBb = __builtin_amdgcn_mfma_f32_16x16x32_f16(wT0[1], rB.v, bC[1], 0,0,0);
                hA0 = tanh_s(DAa[0]); hA1 = tanh_s(DAa[1]); hA2 = tanh_s(DAa[2]); hA3 = tanh_s(DAa[3]);
                hA4 = tanh_s(DAb[0]); hA5 = tanh_s(DAb[1]); hA6 = tanh_s(DAb[2]); hA7 = tanh_s(DAb[3]);
                h2A.v = pack8(hA0, hA1, hA2, hA3, hA4, hA5, hA6, hA7);
                hB0 = tanh_s(DBa[0]); hB1 = tanh_s(DBa[1]); hB2 = tanh_s(DBa[2]); hB3 = tanh_s(DBa[3]);
                hB4 = tanh_s(DBb[0]); hB5 = tanh_s(DBb[1]); hB6 = tanh_s(DBb[2]); hB7 = tanh_s(DBb[3]);
                h2B.v = pack8(hB0, hB1, hB2, hB3, hB4, hB5, hB6, hB7);
            }
        }
        __syncthreads();
    }
#undef PSTEP

    // ---- FC epilogue from the consumer's h2(T-1) registers, both chains ----
    if (wid == 1) {
        float4 fw0 = *reinterpret_cast<const float4*>(fcw + 4 * g);
        float4 fw1 = *reinterpret_cast<const float4*>(fcw + 16 + 4 * g);
        float pA = fw0.x * hA0 + fw0.y * hA1 + fw0.z * hA2 + fw0.w * hA3
                 + fw1.x * hA4 + fw1.y * hA5 + fw1.z * hA6 + fw1.w * hA7;
        float pB = fw0.x * hB0 + fw0.y * hB1 + fw0.z * hB2 + fw0.w * hB3
                 + fw1.x * hB4 + fw1.y * hB5 + fw1.z * hB6 + fw1.w * hB7;
        pA += __shfl_xor(pA, 16, 64);
        pA += __shfl_xor(pA, 32, 64);
        pB += __shfl_xor(pB, 16, 64);
        pB += __shfl_xor(pB, 32, 64);
        if (l < 8) {
            out[rowA + l]     = pA + fcb[0];
            out[rowA + 8 + l] = pB + fcb[0];
        }
    }
}

extern "C" void kernel_launch(void* const* d_in, const int* in_sizes, int n_in,
                              void* d_out, int out_size, void* d_ws, size_t ws_size,
                              hipStream_t stream) {
    const float* x    = (const float*)d_in[0];
    const float* Wih0 = (const float*)d_in[1];
    const float* Whh0 = (const float*)d_in[2];
    const float* bih0 = (const float*)d_in[3];
    const float* bhh0 = (const float*)d_in[4];
    const float* Wih1 = (const float*)d_in[5];
    const float* Whh1 = (const float*)d_in[6];
    const float* bih1 = (const float*)d_in[7];
    const float* bhh1 = (const float*)d_in[8];
    const float* fcw  = (const float*)d_in[9];
    const float* fcb  = (const float*)d_in[10];
    float* out = (float*)d_out;

    dim3 grid(B_DIM / 16);   // 256 blocks x 2 waves; 2 chains of 8 rows per block
    rnn2_dual_pc_kernel<<<grid, 128, 0, stream>>>(x, Wih0, Whh0, bih0, bhh0,
                                                  Wih1, Whh1, bih1, bhh1,
                                                  fcw, fcb, out);
}

// Round 22
// 93.806 us; speedup vs baseline: 1.7252x; 1.7252x over previous
//
#include <hip/hip_runtime.h>

#define T_DIM 512
#define I_DIM 16
#define B_DIM 4096
#define K_CH 32            // steps per chunk (ring = 64 KB, 2 blocks/CU)
#define COLS 8             // real batch cols per block (16-wide tile, 2x dup)
#define SCL 2.885390081777927f   // 2*log2(e), folded into weights/biases

typedef _Float16 f16x8 __attribute__((ext_vector_type(8)));
typedef float f32x4 __attribute__((ext_vector_type(4)));
typedef __fp16 hf2v __attribute__((ext_vector_type(2)));

union Frag { f16x8 v; __fp16 e[8]; uint4 u; };

// pre-activation already scaled by 2*log2(e): tanh = 1 - 2/(exp2(u)+1)
__device__ __forceinline__ float tanh_s(float u) {
    float e = __builtin_amdgcn_exp2f(u);
    return fmaf(-2.f, __builtin_amdgcn_rcpf(e + 1.f), 1.f);
}

__device__ __forceinline__ f16x8 pack8(float a0, float a1, float a2, float a3,
                                       float b0, float b1, float b2, float b3) {
    Frag f;
    hf2v p0 = __builtin_amdgcn_cvt_pkrtz(a0, a1);
    hf2v p1 = __builtin_amdgcn_cvt_pkrtz(a2, a3);
    hf2v p2 = __builtin_amdgcn_cvt_pkrtz(b0, b1);
    hf2v p3 = __builtin_amdgcn_cvt_pkrtz(b2, b3);
    f.e[0] = p0[0]; f.e[1] = p0[1]; f.e[2] = p1[0]; f.e[3] = p1[1];
    f.e[4] = p2[0]; f.e[5] = p2[1]; f.e[6] = p3[0]; f.e[7] = p3[1];
    return f.v;
}
__device__ __forceinline__ f16x8 tanhpack_s(f32x4 a, f32x4 b) {
    return pack8(tanh_s(a[0]), tanh_s(a[1]), tanh_s(a[2]), tanh_s(a[3]),
                 tanh_s(b[0]), tanh_s(b[1]), tanh_s(b[2]), tanh_s(b[3]));
}
// q-permuted A-frag loads (q(8g+j) = 4g+j | 16+4g+j-4), verified r15-r21,
// tanh scale folded in.
__device__ __forceinline__ f16x8 loadWq32s(const float* W, int row, int g) {
    float4 a = *reinterpret_cast<const float4*>(W + row * 32 + 4 * g);
    float4 b = *reinterpret_cast<const float4*>(W + row * 32 + 16 + 4 * g);
    return pack8(a.x*SCL, a.y*SCL, a.z*SCL, a.w*SCL, b.x*SCL, b.y*SCL, b.z*SCL, b.w*SCL);
}
__device__ __forceinline__ f16x8 loadWq16s(const float* W, int row, int g) {
    float4 a = *reinterpret_cast<const float4*>(W + row * 16 + 4 * g);
    return pack8(a.x*SCL, a.y*SCL, a.z*SCL, a.w*SCL, 0.f, 0.f, 0.f, 0.f);
}

// r19 producer-consumer structure with ONE change: the Xacc refresh MFMAs are
// hoisted BEFORE the tanh block (their only dep is the xf pack), so their
// ~34cy latency hides under the 150cy tanh+pack instead of stalling the next
// step's chain-head MFMA. Arithmetic bit-identical to r19.
__global__ void __launch_bounds__(128)
rnn2_pc8r_kernel(const float* __restrict__ x,
                 const float* __restrict__ Wih0, const float* __restrict__ Whh0,
                 const float* __restrict__ bih0, const float* __restrict__ bhh0,
                 const float* __restrict__ Wih1, const float* __restrict__ Whh1,
                 const float* __restrict__ bih1, const float* __restrict__ bhh1,
                 const float* __restrict__ fcw, const float* __restrict__ fcb,
                 float* __restrict__ out)
{
    const int tid = threadIdx.x;
    const int l   = tid & 63;
    const int wid = tid >> 6;
    const int c   = l & 15;
    const int g   = l >> 4;
    const int rowbase = blockIdx.x * COLS;

    __shared__ __fp16 ring[2][K_CH][64][8];   // 64 KB

    f16x8 wT0[2], wT1[2];
    f32x4 bC[2];
    Frag  h1f;
    f32x4 Xacc[2];
    float4 xp0, xp1, xp2, xp3, xp4, xp5, xp6, xp7;
    const float* xlane = nullptr;
    float h20=0.f,h21=0.f,h22=0.f,h23=0.f,h24=0.f,h25=0.f,h26=0.f,h27=0.f;
    Frag h2f; h2f.u = make_uint4(0u, 0u, 0u, 0u);   // h2(-1) = 0

    if (wid == 0) {
#pragma unroll
        for (int tt = 0; tt < 2; ++tt) {
            const int row = c + 16 * tt;
            wT0[tt] = loadWq32s(Whh0, row, g);
            wT1[tt] = loadWq16s(Wih0, row, g);
            const int r0 = 4 * g + 16 * tt;
            float4 bi = *reinterpret_cast<const float4*>(bih0 + r0);
            float4 bh = *reinterpret_cast<const float4*>(bhh0 + r0);
            bC[tt][0] = (bi.x + bh.x) * SCL; bC[tt][1] = (bi.y + bh.y) * SCL;
            bC[tt][2] = (bi.z + bh.z) * SCL; bC[tt][3] = (bi.w + bh.w) * SCL;
        }
        const size_t xcol = rowbase + (c & (COLS - 1));
        xlane = x + xcol * (size_t)(T_DIM * I_DIM) + 4 * g;
    } else {
#pragma unroll
        for (int tt = 0; tt < 2; ++tt) {
            const int row = c + 16 * tt;
            wT0[tt] = loadWq32s(Wih1, row, g);
            wT1[tt] = loadWq32s(Whh1, row, g);
            const int r0 = 4 * g + 16 * tt;
            float4 bi = *reinterpret_cast<const float4*>(bih1 + r0);
            float4 bh = *reinterpret_cast<const float4*>(bhh1 + r0);
            bC[tt][0] = (bi.x + bh.x) * SCL; bC[tt][1] = (bi.y + bh.y) * SCL;
            bC[tt][2] = (bi.z + bh.z) * SCL; bC[tt][3] = (bi.w + bh.w) * SCL;
        }
    }

// PSTEP(t, P): chain MFMAs -> xf pack -> reload -> Xacc MFMAs (hoisted)
//              -> tanh+pack -> ring write
#define PSTEP(t, P)                                                                         \
    {                                                                                       \
        f32x4 D0a = __builtin_amdgcn_mfma_f32_16x16x32_f16(wT0[0], h1f.v, Xacc[0], 0,0,0);  \
        f32x4 D0b = __builtin_amdgcn_mfma_f32_16x16x32_f16(wT0[1], h1f.v, Xacc[1], 0,0,0);  \
        Frag xf; xf.v = pack8((P).x, (P).y, (P).z, (P).w, 0.f, 0.f, 0.f, 0.f);              \
        const int tn = ((t) + 9 < T_DIM) ? (t) + 9 : (T_DIM - 1);                           \
        (P) = *reinterpret_cast<const float4*>(xlane + (size_t)tn * I_DIM);                 \
        Xacc[0] = __builtin_amdgcn_mfma_f32_16x16x32_f16(wT1[0], xf.v, bC[0], 0,0,0);       \
        Xacc[1] = __builtin_amdgcn_mfma_f32_16x16x32_f16(wT1[1], xf.v, bC[1], 0,0,0);       \
        h1f.v = tanhpack_s(D0a, D0b);                                                       \
        *reinterpret_cast<uint4*>(&ring[((t) / K_CH) & 1][(t) & (K_CH - 1)][l][0]) = h1f.u; \
    }

#pragma unroll 1
    for (int p = 0; p <= T_DIM / K_CH; ++p) {
        if (wid == 0 && p < T_DIM / K_CH) {
            if (p == 0) {
                // ---- serial prologue: h1(0..7) with inline x-folds ----
                {
                    float4 xq = *reinterpret_cast<const float4*>(xlane + 0 * I_DIM);
                    Frag xg; xg.v = pack8(xq.x, xq.y, xq.z, xq.w, 0.f, 0.f, 0.f, 0.f);
                    f32x4 A0 = __builtin_amdgcn_mfma_f32_16x16x32_f16(wT1[0], xg.v, bC[0], 0,0,0);
                    f32x4 A1 = __builtin_amdgcn_mfma_f32_16x16x32_f16(wT1[1], xg.v, bC[1], 0,0,0);
                    h1f.v = tanhpack_s(A0, A1);
                    *reinterpret_cast<uint4*>(&ring[0][0][l][0]) = h1f.u;
                }
#pragma unroll
                for (int t = 1; t < 8; ++t) {
                    float4 xq = *reinterpret_cast<const float4*>(xlane + (size_t)t * I_DIM);
                    Frag xg; xg.v = pack8(xq.x, xq.y, xq.z, xq.w, 0.f, 0.f, 0.f, 0.f);
                    f32x4 X0 = __builtin_amdgcn_mfma_f32_16x16x32_f16(wT1[0], xg.v, bC[0], 0,0,0);
                    f32x4 X1 = __builtin_amdgcn_mfma_f32_16x16x32_f16(wT1[1], xg.v, bC[1], 0,0,0);
                    f32x4 D0 = __builtin_amdgcn_mfma_f32_16x16x32_f16(wT0[0], h1f.v, X0, 0,0,0);
                    f32x4 D1 = __builtin_amdgcn_mfma_f32_16x16x32_f16(wT0[1], h1f.v, X1, 0,0,0);
                    h1f.v = tanhpack_s(D0, D1);
                    *reinterpret_cast<uint4*>(&ring[0][t][l][0]) = h1f.u;
                }
                // Xacc = fold x(8); fill 8-deep ring with x(9..16)
                {
                    float4 xq = *reinterpret_cast<const float4*>(xlane + 8 * I_DIM);
                    Frag xg; xg.v = pack8(xq.x, xq.y, xq.z, xq.w, 0.f, 0.f, 0.f, 0.f);
                    Xacc[0] = __builtin_amdgcn_mfma_f32_16x16x32_f16(wT1[0], xg.v, bC[0], 0,0,0);
                    Xacc[1] = __builtin_amdgcn_mfma_f32_16x16x32_f16(wT1[1], xg.v, bC[1], 0,0,0);
                }
                xp0 = *reinterpret_cast<const float4*>(xlane +  9 * I_DIM);
                xp1 = *reinterpret_cast<const float4*>(xlane + 10 * I_DIM);
                xp2 = *reinterpret_cast<const float4*>(xlane + 11 * I_DIM);
                xp3 = *reinterpret_cast<const float4*>(xlane + 12 * I_DIM);
                xp4 = *reinterpret_cast<const float4*>(xlane + 13 * I_DIM);
                xp5 = *reinterpret_cast<const float4*>(xlane + 14 * I_DIM);
                xp6 = *reinterpret_cast<const float4*>(xlane + 15 * I_DIM);
                xp7 = *reinterpret_cast<const float4*>(xlane + 16 * I_DIM);
                // steps 8..31: 24 = 3 groups of 8
#pragma unroll 1
                for (int sgrp = 8; sgrp < K_CH; sgrp += 8) {
                    PSTEP(sgrp + 0, xp0) PSTEP(sgrp + 1, xp1)
                    PSTEP(sgrp + 2, xp2) PSTEP(sgrp + 3, xp3)
                    PSTEP(sgrp + 4, xp4) PSTEP(sgrp + 5, xp5)
                    PSTEP(sgrp + 6, xp6) PSTEP(sgrp + 7, xp7)
                }
            } else {
                const int t0 = p * K_CH;
#pragma unroll 1
                for (int sgrp = 0; sgrp < K_CH; sgrp += 8) {
                    PSTEP(t0 + sgrp + 0, xp0) PSTEP(t0 + sgrp + 1, xp1)
                    PSTEP(t0 + sgrp + 2, xp2) PSTEP(t0 + sgrp + 3, xp3)
                    PSTEP(t0 + sgrp + 4, xp4) PSTEP(t0 + sgrp + 5, xp5)
                    PSTEP(t0 + sgrp + 6, xp6) PSTEP(t0 + sgrp + 7, xp7)
                }
            }
        }
        if (wid == 1 && p >= 1) {
            const int buf = (p - 1) & 1;
            Frag hB; hB.u = *reinterpret_cast<const uint4*>(&ring[buf][0][l][0]);
            f32x4 pd1a = __builtin_amdgcn_mfma_f32_16x16x32_f16(wT0[0], hB.v, bC[0], 0,0,0);
            f32x4 pd1b = __builtin_amdgcn_mfma_f32_16x16x32_f16(wT0[1], hB.v, bC[1], 0,0,0);
#pragma unroll 2
            for (int s = 0; s < K_CH; ++s) {
                f32x4 D1a = __builtin_amdgcn_mfma_f32_16x16x32_f16(wT1[0], h2f.v, pd1a, 0,0,0);
                f32x4 D1b = __builtin_amdgcn_mfma_f32_16x16x32_f16(wT1[1], h2f.v, pd1b, 0,0,0);
                const int sn = (s + 1 < K_CH) ? s + 1 : s;
                hB.u = *reinterpret_cast<const uint4*>(&ring[buf][sn][l][0]);
                pd1a = __builtin_amdgcn_mfma_f32_16x16x32_f16(wT0[0], hB.v, bC[0], 0,0,0);
                pd1b = __builtin_amdgcn_mfma_f32_16x16x32_f16(wT0[1], hB.v, bC[1], 0,0,0);
                h20 = tanh_s(D1a[0]); h21 = tanh_s(D1a[1]);
                h22 = tanh_s(D1a[2]); h23 = tanh_s(D1a[3]);
                h24 = tanh_s(D1b[0]); h25 = tanh_s(D1b[1]);
                h26 = tanh_s(D1b[2]); h27 = tanh_s(D1b[3]);
                h2f.v = pack8(h20, h21, h22, h23, h24, h25, h26, h27);
            }
        }
        __syncthreads();
    }
#undef PSTEP

    // ---- FC epilogue from the consumer's h2(T-1) registers ----
    if (wid == 1) {
        float4 fw0 = *reinterpret_cast<const float4*>(fcw + 4 * g);
        float4 fw1 = *reinterpret_cast<const float4*>(fcw + 16 + 4 * g);
        float part = fw0.x * h20 + fw0.y * h21 + fw0.z * h22 + fw0.w * h23
                   + fw1.x * h24 + fw1.y * h25 + fw1.z * h26 + fw1.w * h27;
        part += __shfl_xor(part, 16, 64);
        part += __shfl_xor(part, 32, 64);
        if (l < COLS) out[rowbase + l] = part + fcb[0];
    }
}

extern "C" void kernel_launch(void* const* d_in, const int* in_sizes, int n_in,
                              void* d_out, int out_size, void* d_ws, size_t ws_size,
                              hipStream_t stream) {
    const float* x    = (const float*)d_in[0];
    const float* Wih0 = (const float*)d_in[1];
    const float* Whh0 = (const float*)d_in[2];
    const float* bih0 = (const float*)d_in[3];
    const float* bhh0 = (const float*)d_in[4];
    const float* Wih1 = (const float*)d_in[5];
    const float* Whh1 = (const float*)d_in[6];
    const float* bih1 = (const float*)d_in[7];
    const float* bhh1 = (const float*)d_in[8];
    const float* fcw  = (const float*)d_in[9];
    const float* fcb  = (const float*)d_in[10];
    float* out = (float*)d_out;

    dim3 grid(B_DIM / COLS);   // 512 blocks x 2 waves = 1024 waves
    rnn2_pc8r_kernel<<<grid, 128, 0, stream>>>(x, Wih0, Whh0, bih0, bhh0,
                                               Wih1, Whh1, bih1, bhh1,
                                               fcw, fcb, out);
}

// Round 23
// 91.764 us; speedup vs baseline: 1.7636x; 1.0222x over previous
//
#include <hip/hip_runtime.h>

#define T_DIM 512
#define I_DIM 16
#define B_DIM 4096
#define K_CH 32            // steps per chunk (ring = 64 KB, 2 blocks/CU)
#define COLS 8             // real batch cols per block (16-wide tile, 2x dup)
#define SCL 2.885390081777927f   // 2*log2(e), folded into weights/biases

typedef _Float16 f16x8 __attribute__((ext_vector_type(8)));
typedef float f32x4 __attribute__((ext_vector_type(4)));
typedef __fp16 hf2v __attribute__((ext_vector_type(2)));

union Frag { f16x8 v; __fp16 e[8]; uint4 u; };

// pre-activation already scaled by 2*log2(e): tanh = 1 - 2/(exp2(u)+1)
__device__ __forceinline__ float tanh_s(float u) {
    float e = __builtin_amdgcn_exp2f(u);
    return fmaf(-2.f, __builtin_amdgcn_rcpf(e + 1.f), 1.f);
}

__device__ __forceinline__ f16x8 pack8(float a0, float a1, float a2, float a3,
                                       float b0, float b1, float b2, float b3) {
    Frag f;
    hf2v p0 = __builtin_amdgcn_cvt_pkrtz(a0, a1);
    hf2v p1 = __builtin_amdgcn_cvt_pkrtz(a2, a3);
    hf2v p2 = __builtin_amdgcn_cvt_pkrtz(b0, b1);
    hf2v p3 = __builtin_amdgcn_cvt_pkrtz(b2, b3);
    f.e[0] = p0[0]; f.e[1] = p0[1]; f.e[2] = p1[0]; f.e[3] = p1[1];
    f.e[4] = p2[0]; f.e[5] = p2[1]; f.e[6] = p3[0]; f.e[7] = p3[1];
    return f.v;
}
__device__ __forceinline__ f16x8 tanhpack_s(f32x4 a, f32x4 b) {
    return pack8(tanh_s(a[0]), tanh_s(a[1]), tanh_s(a[2]), tanh_s(a[3]),
                 tanh_s(b[0]), tanh_s(b[1]), tanh_s(b[2]), tanh_s(b[3]));
}
// q-permuted A-frag loads (q(8g+j) = 4g+j | 16+4g+j-4), verified r15-r22,
// tanh scale folded in.
__device__ __forceinline__ f16x8 loadWq32s(const float* W, int row, int g) {
    float4 a = *reinterpret_cast<const float4*>(W + row * 32 + 4 * g);
    float4 b = *reinterpret_cast<const float4*>(W + row * 32 + 16 + 4 * g);
    return pack8(a.x*SCL, a.y*SCL, a.z*SCL, a.w*SCL, b.x*SCL, b.y*SCL, b.z*SCL, b.w*SCL);
}
__device__ __forceinline__ f16x8 loadWq16s(const float* W, int row, int g) {
    float4 a = *reinterpret_cast<const float4*>(W + row * 16 + 4 * g);
    return pack8(a.x*SCL, a.y*SCL, a.z*SCL, a.w*SCL, 0.f, 0.f, 0.f, 0.f);
}

// Measured-best structure (r19, 91.9us): producer-consumer wave
// specialization, q-relabeled in-register MFMA recurrence, 8-deep x prefetch.
__global__ void __launch_bounds__(128)
rnn2_pc8_kernel(const float* __restrict__ x,
                const float* __restrict__ Wih0, const float* __restrict__ Whh0,
                const float* __restrict__ bih0, const float* __restrict__ bhh0,
                const float* __restrict__ Wih1, const float* __restrict__ Whh1,
                const float* __restrict__ bih1, const float* __restrict__ bhh1,
                const float* __restrict__ fcw, const float* __restrict__ fcb,
                float* __restrict__ out)
{
    const int tid = threadIdx.x;
    const int l   = tid & 63;
    const int wid = tid >> 6;
    const int c   = l & 15;
    const int g   = l >> 4;
    const int rowbase = blockIdx.x * COLS;

    __shared__ __fp16 ring[2][K_CH][64][8];   // 64 KB

    f16x8 wT0[2], wT1[2];
    f32x4 bC[2];
    Frag  h1f;
    f32x4 Xacc[2];
    float4 xp0, xp1, xp2, xp3, xp4, xp5, xp6, xp7;
    const float* xlane = nullptr;
    float h20=0.f,h21=0.f,h22=0.f,h23=0.f,h24=0.f,h25=0.f,h26=0.f,h27=0.f;
    Frag h2f; h2f.u = make_uint4(0u, 0u, 0u, 0u);   // h2(-1) = 0

    if (wid == 0) {
#pragma unroll
        for (int tt = 0; tt < 2; ++tt) {
            const int row = c + 16 * tt;
            wT0[tt] = loadWq32s(Whh0, row, g);
            wT1[tt] = loadWq16s(Wih0, row, g);
            const int r0 = 4 * g + 16 * tt;
            float4 bi = *reinterpret_cast<const float4*>(bih0 + r0);
            float4 bh = *reinterpret_cast<const float4*>(bhh0 + r0);
            bC[tt][0] = (bi.x + bh.x) * SCL; bC[tt][1] = (bi.y + bh.y) * SCL;
            bC[tt][2] = (bi.z + bh.z) * SCL; bC[tt][3] = (bi.w + bh.w) * SCL;
        }
        const size_t xcol = rowbase + (c & (COLS - 1));
        xlane = x + xcol * (size_t)(T_DIM * I_DIM) + 4 * g;
    } else {
#pragma unroll
        for (int tt = 0; tt < 2; ++tt) {
            const int row = c + 16 * tt;
            wT0[tt] = loadWq32s(Wih1, row, g);
            wT1[tt] = loadWq32s(Whh1, row, g);
            const int r0 = 4 * g + 16 * tt;
            float4 bi = *reinterpret_cast<const float4*>(bih1 + r0);
            float4 bh = *reinterpret_cast<const float4*>(bhh1 + r0);
            bC[tt][0] = (bi.x + bh.x) * SCL; bC[tt][1] = (bi.y + bh.y) * SCL;
            bC[tt][2] = (bi.z + bh.z) * SCL; bC[tt][3] = (bi.w + bh.w) * SCL;
        }
    }

// PSTEP(t, P): P holds x(t+1); consume it, reload P = x(t+9) (used at t+8)
#define PSTEP(t, P)                                                                         \
    {                                                                                       \
        f32x4 D0a = __builtin_amdgcn_mfma_f32_16x16x32_f16(wT0[0], h1f.v, Xacc[0], 0,0,0);  \
        f32x4 D0b = __builtin_amdgcn_mfma_f32_16x16x32_f16(wT0[1], h1f.v, Xacc[1], 0,0,0);  \
        Frag xf; xf.v = pack8((P).x, (P).y, (P).z, (P).w, 0.f, 0.f, 0.f, 0.f);              \
        const int tn = ((t) + 9 < T_DIM) ? (t) + 9 : (T_DIM - 1);                           \
        (P) = *reinterpret_cast<const float4*>(xlane + (size_t)tn * I_DIM);                 \
        h1f.v = tanhpack_s(D0a, D0b);                                                       \
        *reinterpret_cast<uint4*>(&ring[((t) / K_CH) & 1][(t) & (K_CH - 1)][l][0]) = h1f.u; \
        Xacc[0] = __builtin_amdgcn_mfma_f32_16x16x32_f16(wT1[0], xf.v, bC[0], 0,0,0);       \
        Xacc[1] = __builtin_amdgcn_mfma_f32_16x16x32_f16(wT1[1], xf.v, bC[1], 0,0,0);       \
    }

#pragma unroll 1
    for (int p = 0; p <= T_DIM / K_CH; ++p) {
        if (wid == 0 && p < T_DIM / K_CH) {
            if (p == 0) {
                // ---- serial prologue: h1(0..7) with inline x-folds ----
                {
                    float4 xq = *reinterpret_cast<const float4*>(xlane + 0 * I_DIM);
                    Frag xg; xg.v = pack8(xq.x, xq.y, xq.z, xq.w, 0.f, 0.f, 0.f, 0.f);
                    f32x4 A0 = __builtin_amdgcn_mfma_f32_16x16x32_f16(wT1[0], xg.v, bC[0], 0,0,0);
                    f32x4 A1 = __builtin_amdgcn_mfma_f32_16x16x32_f16(wT1[1], xg.v, bC[1], 0,0,0);
                    h1f.v = tanhpack_s(A0, A1);
                    *reinterpret_cast<uint4*>(&ring[0][0][l][0]) = h1f.u;
                }
#pragma unroll
                for (int t = 1; t < 8; ++t) {
                    float4 xq = *reinterpret_cast<const float4*>(xlane + (size_t)t * I_DIM);
                    Frag xg; xg.v = pack8(xq.x, xq.y, xq.z, xq.w, 0.f, 0.f, 0.f, 0.f);
                    f32x4 X0 = __builtin_amdgcn_mfma_f32_16x16x32_f16(wT1[0], xg.v, bC[0], 0,0,0);
                    f32x4 X1 = __builtin_amdgcn_mfma_f32_16x16x32_f16(wT1[1], xg.v, bC[1], 0,0,0);
                    f32x4 D0 = __builtin_amdgcn_mfma_f32_16x16x32_f16(wT0[0], h1f.v, X0, 0,0,0);
                    f32x4 D1 = __builtin_amdgcn_mfma_f32_16x16x32_f16(wT0[1], h1f.v, X1, 0,0,0);
                    h1f.v = tanhpack_s(D0, D1);
                    *reinterpret_cast<uint4*>(&ring[0][t][l][0]) = h1f.u;
                }
                // Xacc = fold x(8); fill 8-deep ring with x(9..16)
                {
                    float4 xq = *reinterpret_cast<const float4*>(xlane + 8 * I_DIM);
                    Frag xg; xg.v = pack8(xq.x, xq.y, xq.z, xq.w, 0.f, 0.f, 0.f, 0.f);
                    Xacc[0] = __builtin_amdgcn_mfma_f32_16x16x32_f16(wT1[0], xg.v, bC[0], 0,0,0);
                    Xacc[1] = __builtin_amdgcn_mfma_f32_16x16x32_f16(wT1[1], xg.v, bC[1], 0,0,0);
                }
                xp0 = *reinterpret_cast<const float4*>(xlane +  9 * I_DIM);
                xp1 = *reinterpret_cast<const float4*>(xlane + 10 * I_DIM);
                xp2 = *reinterpret_cast<const float4*>(xlane + 11 * I_DIM);
                xp3 = *reinterpret_cast<const float4*>(xlane + 12 * I_DIM);
                xp4 = *reinterpret_cast<const float4*>(xlane + 13 * I_DIM);
                xp5 = *reinterpret_cast<const float4*>(xlane + 14 * I_DIM);
                xp6 = *reinterpret_cast<const float4*>(xlane + 15 * I_DIM);
                xp7 = *reinterpret_cast<const float4*>(xlane + 16 * I_DIM);
                // steps 8..31: 24 = 3 groups of 8
#pragma unroll 1
                for (int sgrp = 8; sgrp < K_CH; sgrp += 8) {
                    PSTEP(sgrp + 0, xp0) PSTEP(sgrp + 1, xp1)
                    PSTEP(sgrp + 2, xp2) PSTEP(sgrp + 3, xp3)
                    PSTEP(sgrp + 4, xp4) PSTEP(sgrp + 5, xp5)
                    PSTEP(sgrp + 6, xp6) PSTEP(sgrp + 7, xp7)
                }
            } else {
                const int t0 = p * K_CH;
#pragma unroll 1
                for (int sgrp = 0; sgrp < K_CH; sgrp += 8) {
                    PSTEP(t0 + sgrp + 0, xp0) PSTEP(t0 + sgrp + 1, xp1)
                    PSTEP(t0 + sgrp + 2, xp2) PSTEP(t0 + sgrp + 3, xp3)
                    PSTEP(t0 + sgrp + 4, xp4) PSTEP(t0 + sgrp + 5, xp5)
                    PSTEP(t0 + sgrp + 6, xp6) PSTEP(t0 + sgrp + 7, xp7)
                }
            }
        }
        if (wid == 1 && p >= 1) {
            const int buf = (p - 1) & 1;
            Frag hB; hB.u = *reinterpret_cast<const uint4*>(&ring[buf][0][l][0]);
            f32x4 pd1a = __builtin_amdgcn_mfma_f32_16x16x32_f16(wT0[0], hB.v, bC[0], 0,0,0);
            f32x4 pd1b = __builtin_amdgcn_mfma_f32_16x16x32_f16(wT0[1], hB.v, bC[1], 0,0,0);
#pragma unroll 2
            for (int s = 0; s < K_CH; ++s) {
                f32x4 D1a = __builtin_amdgcn_mfma_f32_16x16x32_f16(wT1[0], h2f.v, pd1a, 0,0,0);
                f32x4 D1b = __builtin_amdgcn_mfma_f32_16x16x32_f16(wT1[1], h2f.v, pd1b, 0,0,0);
                const int sn = (s + 1 < K_CH) ? s + 1 : s;
                hB.u = *reinterpret_cast<const uint4*>(&ring[buf][sn][l][0]);
                pd1a = __builtin_amdgcn_mfma_f32_16x16x32_f16(wT0[0], hB.v, bC[0], 0,0,0);
                pd1b = __builtin_amdgcn_mfma_f32_16x16x32_f16(wT0[1], hB.v, bC[1], 0,0,0);
                h20 = tanh_s(D1a[0]); h21 = tanh_s(D1a[1]);
                h22 = tanh_s(D1a[2]); h23 = tanh_s(D1a[3]);
                h24 = tanh_s(D1b[0]); h25 = tanh_s(D1b[1]);
                h26 = tanh_s(D1b[2]); h27 = tanh_s(D1b[3]);
                h2f.v = pack8(h20, h21, h22, h23, h24, h25, h26, h27);
            }
        }
        __syncthreads();
    }
#undef PSTEP

    // ---- FC epilogue from the consumer's h2(T-1) registers ----
    if (wid == 1) {
        float4 fw0 = *reinterpret_cast<const float4*>(fcw + 4 * g);
        float4 fw1 = *reinterpret_cast<const float4*>(fcw + 16 + 4 * g);
        float part = fw0.x * h20 + fw0.y * h21 + fw0.z * h22 + fw0.w * h23
                   + fw1.x * h24 + fw1.y * h25 + fw1.z * h26 + fw1.w * h27;
        part += __shfl_xor(part, 16, 64);
        part += __shfl_xor(part, 32, 64);
        if (l < COLS) out[rowbase + l] = part + fcb[0];
    }
}

extern "C" void kernel_launch(void* const* d_in, const int* in_sizes, int n_in,
                              void* d_out, int out_size, void* d_ws, size_t ws_size,
                              hipStream_t stream) {
    const float* x    = (const float*)d_in[0];
    const float* Wih0 = (const float*)d_in[1];
    const float* Whh0 = (const float*)d_in[2];
    const float* bih0 = (const float*)d_in[3];
    const float* bhh0 = (const float*)d_in[4];
    const float* Wih1 = (const float*)d_in[5];
    const float* Whh1 = (const float*)d_in[6];
    const float* bih1 = (const float*)d_in[7];
    const float* bhh1 = (const float*)d_in[8];
    const float* fcw  = (const float*)d_in[9];
    const float* fcb  = (const float*)d_in[10];
    float* out = (float*)d_out;

    dim3 grid(B_DIM / COLS);   // 512 blocks x 2 waves = 1024 waves
    rnn2_pc8_kernel<<<grid, 128, 0, stream>>>(x, Wih0, Whh0, bih0, bhh0,
                                              Wih1, Whh1, bih1, bhh1,
                                              fcw, fcb, out);
}